// Round 1
// baseline (2286.174 us; speedup 1.0000x reference)
//
#include <hip/hip_runtime.h>
#include <hip/hip_bf16.h>

// Problem: B=2, N=2048, E=1024, H=16, D=64 (MQA: K/V shared across heads).
// out = softmax(mask(Q K^T / 8)) V  -> reshape -> @ Wo + bo
//
// Baseline structure (fp32 everywhere this round):
//   gemm_f32:   C(M,N) = A(M,K) @ B(K,N) [+ bias], 64x64 tile, BK=16, 256 thr, 4x4/thread
//   attn_kernel: flash-style causal attention, one block per (b,h,qtile=64 rows)

#define NQ 2048
#define BATCH 2
#define HEADS 16
#define HD 64
#define EMB 1024

template<bool HAS_BIAS>
__global__ void gemm_f32(const float* __restrict__ A, const float* __restrict__ B,
                         const float* __restrict__ bias, float* __restrict__ C,
                         int M, int N, int K) {
    __shared__ float As[16][65];   // A tile transposed: As[kk][m], +1 pad vs bank conflicts
    __shared__ float Bs[16][64];   // B tile: Bs[kk][n]
    const int t = threadIdx.x;
    const int row0 = blockIdx.y * 64, col0 = blockIdx.x * 64;
    const int tx = t & 15, ty = t >> 4;
    float acc[4][4] = {};
    for (int k0 = 0; k0 < K; k0 += 16) {
        {   // A tile: 64 rows x 16 k, one float4 per thread
            int m  = t >> 2;
            int kk = (t & 3) * 4;
            const float4 a = *(const float4*)&A[(size_t)(row0 + m) * K + k0 + kk];
            As[kk + 0][m] = a.x; As[kk + 1][m] = a.y;
            As[kk + 2][m] = a.z; As[kk + 3][m] = a.w;
        }
        {   // B tile: 16 k x 64 n, one float4 per thread
            int kk = t >> 4;
            int n  = (t & 15) * 4;
            *(float4*)&Bs[kk][n] = *(const float4*)&B[(size_t)(k0 + kk) * N + col0 + n];
        }
        __syncthreads();
#pragma unroll
        for (int kk = 0; kk < 16; ++kk) {
            float ra[4], rb[4];
#pragma unroll
            for (int i = 0; i < 4; ++i) ra[i] = As[kk][ty * 4 + i];
#pragma unroll
            for (int j = 0; j < 4; ++j) rb[j] = Bs[kk][tx * 4 + j];
#pragma unroll
            for (int i = 0; i < 4; ++i)
#pragma unroll
                for (int j = 0; j < 4; ++j)
                    acc[i][j] += ra[i] * rb[j];
        }
        __syncthreads();
    }
#pragma unroll
    for (int i = 0; i < 4; ++i) {
        const int r = row0 + ty * 4 + i;
#pragma unroll
        for (int j = 0; j < 4; ++j) {
            const int c = col0 + tx * 4 + j;
            float v = acc[i][j];
            if (HAS_BIAS) v += bias[c];
            C[(size_t)r * N + c] = v;
        }
    }
}

// Flash-style causal MQA attention.
// grid = (N/64, H, B), block = 256.
// Thread t owns query row r = t>>2 of the tile and a 16-wide slice (t&3)*16 of
// cols (keys for S, head-dims for O). Row-reductions via __shfl_xor over the
// 4-thread group (same wave: lanes 4r..4r+3).
__global__ void attn_kernel(const float* __restrict__ Q, const float* __restrict__ K,
                            const float* __restrict__ V, float* __restrict__ Z) {
    const int qt = blockIdx.x, h = blockIdx.y, b = blockIdx.z;
    __shared__ float Qs[64][65];
    __shared__ float Ks[64][65];   // reused as P (probabilities) after S-compute
    __shared__ float Vs[64][65];
    const int t  = threadIdx.x;
    const int r  = t >> 2;
    const int cb = (t & 3) * 16;

    // Load Q tile: rows b*N + qt*64 + rr, cols h*64 + d
    for (int i = t; i < 64 * 64; i += 256) {
        const int rr = i >> 6, d = i & 63;
        Qs[rr][d] = Q[(size_t)(b * NQ + qt * 64 + rr) * (HEADS * HD) + h * HD + d];
    }

    float o[16];
#pragma unroll
    for (int i = 0; i < 16; ++i) o[i] = 0.f;
    float m = -1e30f, l = 0.f;
    const float scale = 0.125f;   // 1/sqrt(64)
    __syncthreads();

    for (int jt = 0; jt <= qt; ++jt) {
        // Load K/V tiles (64 rows x 64 dims each)
        for (int i = t; i < 64 * 64; i += 256) {
            const int rr = i >> 6, d = i & 63;
            const size_t g = (size_t)(b * NQ + jt * 64 + rr) * HD + d;
            Ks[rr][d] = K[g];
            Vs[rr][d] = V[g];
        }
        __syncthreads();

        // S[r][cb+ci] = sum_d Q[r][d] * K[cb+ci][d]
        float s[16];
#pragma unroll
        for (int ci = 0; ci < 16; ++ci) s[ci] = 0.f;
        for (int d = 0; d < 64; ++d) {
            const float q = Qs[r][d];
#pragma unroll
            for (int ci = 0; ci < 16; ++ci) s[ci] += q * Ks[cb + ci][d];
        }

        // scale + causal mask + online softmax
        float rowmax = -1e30f;
#pragma unroll
        for (int ci = 0; ci < 16; ++ci) {
            s[ci] *= scale;
            if (jt == qt && (cb + ci) > r) s[ci] = -1e30f;
            rowmax = fmaxf(rowmax, s[ci]);
        }
        rowmax = fmaxf(rowmax, __shfl_xor(rowmax, 1));
        rowmax = fmaxf(rowmax, __shfl_xor(rowmax, 2));
        const float mnew  = fmaxf(m, rowmax);
        const float alpha = __expf(m - mnew);
        float rowsum = 0.f;
#pragma unroll
        for (int ci = 0; ci < 16; ++ci) {
            s[ci] = __expf(s[ci] - mnew);
            rowsum += s[ci];
        }
        rowsum += __shfl_xor(rowsum, 1);
        rowsum += __shfl_xor(rowsum, 2);
        l = l * alpha + rowsum;
        m = mnew;
#pragma unroll
        for (int i = 0; i < 16; ++i) o[i] *= alpha;

        // Stage P into Ks (dead after S-compute); barrier protects readers first.
        __syncthreads();
#pragma unroll
        for (int ci = 0; ci < 16; ++ci) Ks[r][cb + ci] = s[ci];
        __syncthreads();

        // O[r][cb+i] += sum_j P[r][j] * V[j][cb+i]
        for (int j = 0; j < 64; ++j) {
            const float p = Ks[r][j];
#pragma unroll
            for (int i = 0; i < 16; ++i) o[i] += p * Vs[j][cb + i];
        }
        __syncthreads();   // before next iteration overwrites Ks/Vs
    }

    const float inv_l = 1.f / l;
#pragma unroll
    for (int i = 0; i < 16; ++i)
        Z[(size_t)(b * NQ + qt * 64 + r) * (HEADS * HD) + h * HD + cb + i] = o[i] * inv_l;
}

extern "C" void kernel_launch(void* const* d_in, const int* in_sizes, int n_in,
                              void* d_out, int out_size, void* d_ws, size_t ws_size,
                              hipStream_t stream) {
    const float* x  = (const float*)d_in[0];   // (B,N,E) = (4096,1024) rows
    const float* Wq = (const float*)d_in[1];   // (1024,1024)
    const float* Wk = (const float*)d_in[2];   // (1024,64)
    const float* Wv = (const float*)d_in[3];   // (1024,64)
    const float* Wo = (const float*)d_in[4];   // (1024,1024)
    const float* bo = (const float*)d_in[5];   // (1024,)
    float* out = (float*)d_out;

    const int M = BATCH * NQ;                  // 4096
    char* ws = (char*)d_ws;
    float* Qb = (float*)ws;                               // 4096x1024 = 16 MB
    float* Kb = (float*)(ws + (size_t)M * EMB * 4);       //  4096x64  =  1 MB
    float* Vb = Kb + (size_t)M * HD;                      //  4096x64  =  1 MB
    float* Zb = Vb + (size_t)M * HD;                      // 4096x1024 = 16 MB

    dim3 blk(256);
    // Projections
    gemm_f32<false><<<dim3(EMB / 64, M / 64), blk, 0, stream>>>(x, Wq, nullptr, Qb, M, EMB, EMB);
    gemm_f32<false><<<dim3(1,        M / 64), blk, 0, stream>>>(x, Wk, nullptr, Kb, M, HD,  EMB);
    gemm_f32<false><<<dim3(1,        M / 64), blk, 0, stream>>>(x, Wv, nullptr, Vb, M, HD,  EMB);
    // Attention
    attn_kernel<<<dim3(NQ / 64, HEADS, BATCH), blk, 0, stream>>>(Qb, Kb, Vb, Zb);
    // Output projection + bias
    gemm_f32<true><<<dim3(EMB / 64, M / 64), blk, 0, stream>>>(Zb, Wo, bo, out, M, EMB, EMB);
}

// Round 2
// 562.242 us; speedup vs baseline: 4.0662x; 4.0662x over previous
//
#include <hip/hip_runtime.h>
#include <hip/hip_bf16.h>

// B=2, N=2048, E=1024, H=16, D=64 (MQA). out = softmax(causal(QK^T/8)) V @ Wo + bo
//
// Round 1: attention -> flash-style bf16 MFMA (16x16x32), projections emit bf16.
//   gemm_f32<bias,OutT>: fp32 tiled GEMM, optionally storing bf16.
//   attn_mfma: 1 block per (b,h,64-query tile); 4 waves x 16 query rows;
//              K/V tiles staged in LDS (V transposed), online softmax in regs,
//              P round-trips through per-wave LDS into A-operand layout.

#define NQ 2048
#define BATCH 2
#define HEADS 16
#define HD 64
#define EMB 1024

typedef short s16x8 __attribute__((ext_vector_type(8)));
typedef float f32x4 __attribute__((ext_vector_type(4)));
typedef unsigned short ushort_t;

__device__ __forceinline__ ushort_t f2bf(float f) {
    unsigned u = __builtin_bit_cast(unsigned, f);
    u += 0x7fff + ((u >> 16) & 1);          // RNE; inputs are well-behaved (no NaN)
    return (ushort_t)(u >> 16);
}

__device__ __forceinline__ void store_out(float* p, float v) { *p = v; }
__device__ __forceinline__ void store_out(ushort_t* p, float v) { *p = f2bf(v); }

template<bool HAS_BIAS, typename OutT>
__global__ void gemm_f32(const float* __restrict__ A, const float* __restrict__ B,
                         const float* __restrict__ bias, OutT* __restrict__ C,
                         int M, int N, int K) {
    __shared__ float As[16][65];
    __shared__ float Bs[16][64];
    const int t = threadIdx.x;
    const int row0 = blockIdx.y * 64, col0 = blockIdx.x * 64;
    const int tx = t & 15, ty = t >> 4;
    float acc[4][4] = {};
    for (int k0 = 0; k0 < K; k0 += 16) {
        {
            int m  = t >> 2;
            int kk = (t & 3) * 4;
            const float4 a = *(const float4*)&A[(size_t)(row0 + m) * K + k0 + kk];
            As[kk + 0][m] = a.x; As[kk + 1][m] = a.y;
            As[kk + 2][m] = a.z; As[kk + 3][m] = a.w;
        }
        {
            int kk = t >> 4;
            int n  = (t & 15) * 4;
            *(float4*)&Bs[kk][n] = *(const float4*)&B[(size_t)(k0 + kk) * N + col0 + n];
        }
        __syncthreads();
#pragma unroll
        for (int kk = 0; kk < 16; ++kk) {
            float ra[4], rb[4];
#pragma unroll
            for (int i = 0; i < 4; ++i) ra[i] = As[kk][ty * 4 + i];
#pragma unroll
            for (int j = 0; j < 4; ++j) rb[j] = Bs[kk][tx * 4 + j];
#pragma unroll
            for (int i = 0; i < 4; ++i)
#pragma unroll
                for (int j = 0; j < 4; ++j)
                    acc[i][j] += ra[i] * rb[j];
        }
        __syncthreads();
    }
#pragma unroll
    for (int i = 0; i < 4; ++i) {
        const int r = row0 + ty * 4 + i;
#pragma unroll
        for (int j = 0; j < 4; ++j) {
            const int c = col0 + tx * 4 + j;
            float v = acc[i][j];
            if (HAS_BIAS) v += bias[c];
            store_out(&C[(size_t)r * N + c], v);
        }
    }
}

// Flash attention with bf16 MFMA.
// grid = (N/64, H, B), block = 256 (4 waves). Wave w owns query rows w*16..w*16+15.
// MFMA 16x16x32 layouts (HW-verified per guide):
//   A[m][k]: m = lane&15, k = (lane>>4)*8 + j   (8 contiguous k per lane)
//   B[k][n]: n = lane&15, k = (lane>>4)*8 + j
//   C/D:     col = lane&15, row = (lane>>4)*4 + reg
__global__ __launch_bounds__(256) void attn_mfma(const ushort_t* __restrict__ Q,
                                                 const ushort_t* __restrict__ K,
                                                 const ushort_t* __restrict__ V,
                                                 float* __restrict__ Z) {
    const int qt = blockIdx.x, h = blockIdx.y, b = blockIdx.z;
    const int t = threadIdx.x;
    const int w = t >> 6, lane = t & 63, quad = lane >> 4, ln = lane & 15;

    // 72-elem stride: keeps 16B alignment for b128 ops, spreads banks (144B row).
    __shared__ __align__(16) ushort_t Qs[64][72];
    __shared__ __align__(16) ushort_t Ks[64][72];
    __shared__ __align__(16) ushort_t Vt[64][72];      // Vt[dim][key]
    __shared__ __align__(16) ushort_t Ps[4][16][72];   // per-wave P tile

    // Stage Q tile (64 rows x 64 dims): 8 bf16 per thread-chunk, 2 chunks.
#pragma unroll
    for (int it = 0; it < 2; ++it) {
        const int idx = t + it * 256;
        const int r = idx >> 3, c = (idx & 7) * 8;
        *(uint4*)&Qs[r][c] =
            *(const uint4*)&Q[(size_t)(b * NQ + qt * 64 + r) * EMB + h * HD + c];
    }
    __syncthreads();

    const s16x8 aQ0 = *(const s16x8*)&Qs[w * 16 + ln][quad * 8];
    const s16x8 aQ1 = *(const s16x8*)&Qs[w * 16 + ln][32 + quad * 8];

    f32x4 o[4];
#pragma unroll
    for (int i = 0; i < 4; ++i) o[i] = f32x4{0.f, 0.f, 0.f, 0.f};
    float mrow[4], lrow[4];
#pragma unroll
    for (int r = 0; r < 4; ++r) { mrow[r] = -1e30f; lrow[r] = 0.f; }

    for (int jt = 0; jt <= qt; ++jt) {
        __syncthreads();   // prior iteration's Ks/Vt readers done
        // Stage K tile [key][dim]
#pragma unroll
        for (int it = 0; it < 2; ++it) {
            const int idx = t + it * 256;
            const int r = idx >> 3, c = (idx & 7) * 8;
            *(uint4*)&Ks[r][c] =
                *(const uint4*)&K[(size_t)(b * NQ + jt * 64 + r) * HD + c];
        }
        // Stage V transposed -> Vt[dim][key]: coalesced 2B reads, b128 LDS writes.
        {
            const int d = t & 63, kb = (t >> 6) * 16;
            ushort_t tmp[16];
#pragma unroll
            for (int j = 0; j < 16; ++j)
                tmp[j] = V[(size_t)(b * NQ + jt * 64 + kb + j) * HD + d];
            *(uint4*)&Vt[d][kb]     = *(uint4*)&tmp[0];
            *(uint4*)&Vt[d][kb + 8] = *(uint4*)&tmp[8];
        }
        __syncthreads();

        // S = Q K^T : 4 n-tiles of 16 keys, K-dim = 64 = 2 MFMA steps.
        f32x4 s[4];
#pragma unroll
        for (int nt = 0; nt < 4; ++nt) {
            f32x4 acc = f32x4{0.f, 0.f, 0.f, 0.f};
            const s16x8 b0 = *(const s16x8*)&Ks[nt * 16 + ln][quad * 8];
            const s16x8 b1 = *(const s16x8*)&Ks[nt * 16 + ln][32 + quad * 8];
            acc = __builtin_amdgcn_mfma_f32_16x16x32_bf16(aQ0, b0, acc, 0, 0, 0);
            acc = __builtin_amdgcn_mfma_f32_16x16x32_bf16(aQ1, b1, acc, 0, 0, 0);
            s[nt] = acc;
        }

        // Scale + causal mask + online softmax (rows = quad*4+reg of wave tile).
        const bool diag = (jt == qt);
        float rmax[4];
#pragma unroll
        for (int r = 0; r < 4; ++r) rmax[r] = -1e30f;
#pragma unroll
        for (int nt = 0; nt < 4; ++nt)
#pragma unroll
            for (int r = 0; r < 4; ++r) {
                float v = s[nt][r] * 0.125f;
                if (diag && (nt * 16 + ln) > (w * 16 + quad * 4 + r)) v = -1e30f;
                s[nt][r] = v;
                rmax[r] = fmaxf(rmax[r], v);
            }
#pragma unroll
        for (int r = 0; r < 4; ++r) {
            rmax[r] = fmaxf(rmax[r], __shfl_xor(rmax[r], 1));
            rmax[r] = fmaxf(rmax[r], __shfl_xor(rmax[r], 2));
            rmax[r] = fmaxf(rmax[r], __shfl_xor(rmax[r], 4));
            rmax[r] = fmaxf(rmax[r], __shfl_xor(rmax[r], 8));
        }
        float alpha[4], rsum[4];
#pragma unroll
        for (int r = 0; r < 4; ++r) {
            const float mnew = fmaxf(mrow[r], rmax[r]);
            alpha[r] = __expf(mrow[r] - mnew);
            mrow[r] = mnew;
            rsum[r] = 0.f;
        }
#pragma unroll
        for (int nt = 0; nt < 4; ++nt)
#pragma unroll
            for (int r = 0; r < 4; ++r) {
                const float p = __expf(s[nt][r] - mrow[r]);
                s[nt][r] = p;
                rsum[r] += p;
            }
#pragma unroll
        for (int r = 0; r < 4; ++r) {
            rsum[r] += __shfl_xor(rsum[r], 1);
            rsum[r] += __shfl_xor(rsum[r], 2);
            rsum[r] += __shfl_xor(rsum[r], 4);
            rsum[r] += __shfl_xor(rsum[r], 8);
            lrow[r] = lrow[r] * alpha[r] + rsum[r];
        }
#pragma unroll
        for (int ntd = 0; ntd < 4; ++ntd)
#pragma unroll
            for (int r = 0; r < 4; ++r) o[ntd][r] *= alpha[r];

        // P -> per-wave LDS (C-layout write), re-read in A-layout. In-wave only:
        // DS ops from one wave execute in order; fence stops compiler reordering.
#pragma unroll
        for (int nt = 0; nt < 4; ++nt)
#pragma unroll
            for (int r = 0; r < 4; ++r)
                Ps[w][quad * 4 + r][nt * 16 + ln] = f2bf(s[nt][r]);
        asm volatile("s_waitcnt lgkmcnt(0)" ::: "memory");

        const s16x8 aP0 = *(const s16x8*)&Ps[w][ln][quad * 8];
        const s16x8 aP1 = *(const s16x8*)&Ps[w][ln][32 + quad * 8];
#pragma unroll
        for (int ntd = 0; ntd < 4; ++ntd) {
            const s16x8 b0 = *(const s16x8*)&Vt[ntd * 16 + ln][quad * 8];
            const s16x8 b1 = *(const s16x8*)&Vt[ntd * 16 + ln][32 + quad * 8];
            o[ntd] = __builtin_amdgcn_mfma_f32_16x16x32_bf16(aP0, b0, o[ntd], 0, 0, 0);
            o[ntd] = __builtin_amdgcn_mfma_f32_16x16x32_bf16(aP1, b1, o[ntd], 0, 0, 0);
        }
    }

    float invl[4];
#pragma unroll
    for (int r = 0; r < 4; ++r) invl[r] = 1.f / lrow[r];
#pragma unroll
    for (int ntd = 0; ntd < 4; ++ntd)
#pragma unroll
        for (int r = 0; r < 4; ++r) {
            const size_t row = (size_t)(b * NQ + qt * 64 + w * 16 + quad * 4 + r);
            Z[row * EMB + h * HD + ntd * 16 + ln] = o[ntd][r] * invl[r];
        }
}

extern "C" void kernel_launch(void* const* d_in, const int* in_sizes, int n_in,
                              void* d_out, int out_size, void* d_ws, size_t ws_size,
                              hipStream_t stream) {
    const float* x  = (const float*)d_in[0];
    const float* Wq = (const float*)d_in[1];
    const float* Wk = (const float*)d_in[2];
    const float* Wv = (const float*)d_in[3];
    const float* Wo = (const float*)d_in[4];
    const float* bo = (const float*)d_in[5];
    float* out = (float*)d_out;

    const int M = BATCH * NQ;                               // 4096
    char* ws = (char*)d_ws;
    ushort_t* Qb = (ushort_t*)ws;                           // 4096x1024 bf16 = 8 MB
    ushort_t* Kb = (ushort_t*)(ws + (size_t)8 * 1024 * 1024);      // 4096x64 bf16
    ushort_t* Vb = Kb + (size_t)M * HD;                     // 4096x64 bf16
    float*    Zb = (float*)(ws + (size_t)9 * 1024 * 1024);  // 4096x1024 f32 = 16 MB

    dim3 blk(256);
    gemm_f32<false, ushort_t><<<dim3(EMB / 64, M / 64), blk, 0, stream>>>(x, Wq, nullptr, Qb, M, EMB, EMB);
    gemm_f32<false, ushort_t><<<dim3(1,        M / 64), blk, 0, stream>>>(x, Wk, nullptr, Kb, M, HD,  EMB);
    gemm_f32<false, ushort_t><<<dim3(1,        M / 64), blk, 0, stream>>>(x, Wv, nullptr, Vb, M, HD,  EMB);
    attn_mfma<<<dim3(NQ / 64, HEADS, BATCH), blk, 0, stream>>>(Qb, Kb, Vb, Zb);
    gemm_f32<true, float><<<dim3(EMB / 64, M / 64), blk, 0, stream>>>(Zb, Wo, bo, out, M, EMB, EMB);
}

// Round 3
// 276.686 us; speedup vs baseline: 8.2627x; 2.0321x over previous
//
#include <hip/hip_runtime.h>
#include <hip/hip_bf16.h>

// B=2, N=2048, E=1024, H=16, D=64 (MQA). out = softmax(causal(QK^T/8)) V @ Wo + bo
//
// Round 3: all big GEMMs on MFMA.
//   convert_bf16:    x fp32 -> bf16 (row-major)
//   transpose_bf16:  W fp32 (K x N) -> bf16 W^T (N x K); Wq/Wk/Wv packed into Wqkv_t
//   gemm_bf16:       C(M,N) = A(M,K)bf16 @ B^T(N,K)bf16, 128x128x32 tile,
//                    global_load_lds w=16, XOR-swizzled LDS chunks (2-way max)
//   attn_mfma:       flash attention (unchanged math), packed-QKV in, bf16 Z out

#define NQ 2048
#define BATCH 2
#define HEADS 16
#define HD 64
#define EMB 1024
#define NKV 1152   // 1024 Q cols + 64 K + 64 V

typedef short s16x8 __attribute__((ext_vector_type(8)));
typedef float f32x4 __attribute__((ext_vector_type(4)));
typedef unsigned short ushort_t;

__device__ __forceinline__ ushort_t f2bf(float f) {
    unsigned u = __builtin_bit_cast(unsigned, f);
    u += 0x7fff + ((u >> 16) & 1);          // RNE
    return (ushort_t)(u >> 16);
}

__device__ __forceinline__ void store_out(float* p, float v) { *p = v; }
__device__ __forceinline__ void store_out(ushort_t* p, float v) { *p = f2bf(v); }

// async global->LDS, 16B per lane. LDS dest = wave-uniform base + lane*16.
#define GL16(g, l)                                                                  \
    __builtin_amdgcn_global_load_lds(                                               \
        (const __attribute__((address_space(1))) unsigned int*)(g),                 \
        (__attribute__((address_space(3))) unsigned int*)(l), 16, 0, 0)

__global__ void convert_bf16(const float* __restrict__ src, ushort_t* __restrict__ dst) {
    const int i = (blockIdx.x * 256 + threadIdx.x) * 4;
    const float4 v = *(const float4*)&src[i];
    ushort_t o[4] = {f2bf(v.x), f2bf(v.y), f2bf(v.z), f2bf(v.w)};
    *(uint2*)&dst[i] = *(uint2*)o;
}

// dst[n][k] = src[k][n] (fp32 -> bf16). src: K x N row-major; dst row stride = dstride.
__global__ void transpose_bf16(const float* __restrict__ src, ushort_t* __restrict__ dst,
                               int K, int N, int dstride) {
    __shared__ float tile[32][33];
    const int k0 = blockIdx.y * 32, n0 = blockIdx.x * 32;
    const int tx = threadIdx.x & 31, ty = threadIdx.x >> 5;   // 256 thr: ty 0..7
#pragma unroll
    for (int i = 0; i < 32; i += 8)
        tile[ty + i][tx] = src[(size_t)(k0 + ty + i) * N + n0 + tx];
    __syncthreads();
#pragma unroll
    for (int i = 0; i < 32; i += 8)
        dst[(size_t)(n0 + ty + i) * dstride + k0 + tx] = f2bf(tile[tx][ty + i]);
}

// bf16 MFMA GEMM: C(M,N) = A(M,K) @ Bt(N,K)^T [+ bias].
// 128x128 tile, BK=32, 256 thr = 2x2 waves, each wave 64x64 (4x4 mfma 16x16x32).
// LDS layout: [row][chunk], chunk = 16B of k; physical chunk = logical ^ ((row>>1)&3)
// (swizzle applied on the global gather side; fragment ds_read_b128 is 2-way max).
template<bool HAS_BIAS, typename OutT>
__global__ __launch_bounds__(256) void gemm_bf16(const ushort_t* __restrict__ A,
                                                 const ushort_t* __restrict__ Bt,
                                                 const float* __restrict__ bias,
                                                 OutT* __restrict__ C,
                                                 int M, int N, int K) {
    __shared__ __align__(16) ushort_t Al[128 * 32];
    __shared__ __align__(16) ushort_t Bl[128 * 32];
    const int t = threadIdx.x;
    const int w = t >> 6, lane = t & 63, quad = lane >> 4, ln = lane & 15;
    const int wm = w >> 1, wn = w & 1;
    const int row0 = blockIdx.y * 128, col0 = blockIdx.x * 128;

    // staging: inst i covers chunks u = i*256 + t; row = u>>2, phys chunk = u&3,
    // logical chunk = (u&3) ^ ((row>>1)&3)
    const int r0 = t >> 2, r1 = (t + 256) >> 2;
    const int lc0 = (t & 3) ^ ((r0 >> 1) & 3);
    const int lc1 = (t & 3) ^ ((r1 >> 1) & 3);
    const ushort_t* ga0 = A + (size_t)(row0 + r0) * K + lc0 * 8;
    const ushort_t* ga1 = A + (size_t)(row0 + r1) * K + lc1 * 8;
    const ushort_t* gb0 = Bt + (size_t)(col0 + r0) * K + lc0 * 8;
    const ushort_t* gb1 = Bt + (size_t)(col0 + r1) * K + lc1 * 8;
    ushort_t* lA0 = Al + w * 512;           // inst0: byte base w*1024
    ushort_t* lA1 = Al + 2048 + w * 512;    // inst1: byte base 4096 + w*1024
    ushort_t* lB0 = Bl + w * 512;
    ushort_t* lB1 = Bl + 2048 + w * 512;

    f32x4 acc[4][4] = {};
    const int sw = (ln >> 1) & 3;           // row-swizzle within a 16-row group
    for (int k0 = 0; k0 < K; k0 += 32) {
        GL16(ga0, lA0); GL16(ga1, lA1);
        GL16(gb0, lB0); GL16(gb1, lB1);
        ga0 += 32; ga1 += 32; gb0 += 32; gb1 += 32;
        __syncthreads();

        s16x8 af[4], bf[4];
#pragma unroll
        for (int mt = 0; mt < 4; ++mt) {
            const int r = wm * 64 + mt * 16 + ln;
            af[mt] = *(const s16x8*)&Al[r * 32 + ((quad ^ sw) * 8)];
        }
#pragma unroll
        for (int nt = 0; nt < 4; ++nt) {
            const int r = wn * 64 + nt * 16 + ln;
            bf[nt] = *(const s16x8*)&Bl[r * 32 + ((quad ^ sw) * 8)];
        }
#pragma unroll
        for (int mt = 0; mt < 4; ++mt)
#pragma unroll
            for (int nt = 0; nt < 4; ++nt)
                acc[mt][nt] = __builtin_amdgcn_mfma_f32_16x16x32_bf16(
                    af[mt], bf[nt], acc[mt][nt], 0, 0, 0);
        __syncthreads();
    }

#pragma unroll
    for (int nt = 0; nt < 4; ++nt) {
        const int col = col0 + wn * 64 + nt * 16 + ln;
        const float bv = HAS_BIAS ? bias[col] : 0.f;
#pragma unroll
        for (int mt = 0; mt < 4; ++mt)
#pragma unroll
            for (int r = 0; r < 4; ++r) {
                const int row = row0 + wm * 64 + mt * 16 + quad * 4 + r;
                store_out(&C[(size_t)row * N + col], acc[mt][nt][r] + bv);
            }
    }
}

// Flash attention, bf16 MFMA 16x16x32. QKV packed: row stride NKV;
// Q at col h*64, K at 1024, V at 1088. Z out bf16 row-major 4096x1024.
__global__ __launch_bounds__(256) void attn_mfma(const ushort_t* __restrict__ QKV,
                                                 ushort_t* __restrict__ Z) {
    const int qt = (int)gridDim.x - 1 - (int)blockIdx.x;   // heavy tiles first
    const int h = blockIdx.y, b = blockIdx.z;
    const int t = threadIdx.x;
    const int w = t >> 6, lane = t & 63, quad = lane >> 4, ln = lane & 15;

    __shared__ __align__(16) ushort_t Qs[64][72];
    __shared__ __align__(16) ushort_t Ks[64][72];
    __shared__ __align__(16) ushort_t Vt[64][72];      // Vt[dim][key]
    __shared__ __align__(16) ushort_t Ps[4][16][72];   // per-wave P tile

#pragma unroll
    for (int it = 0; it < 2; ++it) {
        const int idx = t + it * 256;
        const int r = idx >> 3, c = (idx & 7) * 8;
        *(uint4*)&Qs[r][c] =
            *(const uint4*)&QKV[(size_t)(b * NQ + qt * 64 + r) * NKV + h * HD + c];
    }
    __syncthreads();

    const s16x8 aQ0 = *(const s16x8*)&Qs[w * 16 + ln][quad * 8];
    const s16x8 aQ1 = *(const s16x8*)&Qs[w * 16 + ln][32 + quad * 8];

    f32x4 o[4];
#pragma unroll
    for (int i = 0; i < 4; ++i) o[i] = f32x4{0.f, 0.f, 0.f, 0.f};
    float mrow[4], lrow[4];
#pragma unroll
    for (int r = 0; r < 4; ++r) { mrow[r] = -1e30f; lrow[r] = 0.f; }

    for (int jt = 0; jt <= qt; ++jt) {
        __syncthreads();
#pragma unroll
        for (int it = 0; it < 2; ++it) {
            const int idx = t + it * 256;
            const int r = idx >> 3, c = (idx & 7) * 8;
            *(uint4*)&Ks[r][c] =
                *(const uint4*)&QKV[(size_t)(b * NQ + jt * 64 + r) * NKV + 1024 + c];
        }
        {
            const int d = t & 63, kb = (t >> 6) * 16;
            ushort_t tmp[16];
#pragma unroll
            for (int j = 0; j < 16; ++j)
                tmp[j] = QKV[(size_t)(b * NQ + jt * 64 + kb + j) * NKV + 1088 + d];
            *(uint4*)&Vt[d][kb]     = *(uint4*)&tmp[0];
            *(uint4*)&Vt[d][kb + 8] = *(uint4*)&tmp[8];
        }
        __syncthreads();

        f32x4 s[4];
#pragma unroll
        for (int nt = 0; nt < 4; ++nt) {
            f32x4 acc = f32x4{0.f, 0.f, 0.f, 0.f};
            const s16x8 b0 = *(const s16x8*)&Ks[nt * 16 + ln][quad * 8];
            const s16x8 b1 = *(const s16x8*)&Ks[nt * 16 + ln][32 + quad * 8];
            acc = __builtin_amdgcn_mfma_f32_16x16x32_bf16(aQ0, b0, acc, 0, 0, 0);
            acc = __builtin_amdgcn_mfma_f32_16x16x32_bf16(aQ1, b1, acc, 0, 0, 0);
            s[nt] = acc;
        }

        const bool diag = (jt == qt);
        float rmax[4];
#pragma unroll
        for (int r = 0; r < 4; ++r) rmax[r] = -1e30f;
#pragma unroll
        for (int nt = 0; nt < 4; ++nt)
#pragma unroll
            for (int r = 0; r < 4; ++r) {
                float v = s[nt][r] * 0.125f;
                if (diag && (nt * 16 + ln) > (w * 16 + quad * 4 + r)) v = -1e30f;
                s[nt][r] = v;
                rmax[r] = fmaxf(rmax[r], v);
            }
#pragma unroll
        for (int r = 0; r < 4; ++r) {
            rmax[r] = fmaxf(rmax[r], __shfl_xor(rmax[r], 1));
            rmax[r] = fmaxf(rmax[r], __shfl_xor(rmax[r], 2));
            rmax[r] = fmaxf(rmax[r], __shfl_xor(rmax[r], 4));
            rmax[r] = fmaxf(rmax[r], __shfl_xor(rmax[r], 8));
        }
        float alpha[4], rsum[4];
#pragma unroll
        for (int r = 0; r < 4; ++r) {
            const float mnew = fmaxf(mrow[r], rmax[r]);
            alpha[r] = __expf(mrow[r] - mnew);
            mrow[r] = mnew;
            rsum[r] = 0.f;
        }
#pragma unroll
        for (int nt = 0; nt < 4; ++nt)
#pragma unroll
            for (int r = 0; r < 4; ++r) {
                const float p = __expf(s[nt][r] - mrow[r]);
                s[nt][r] = p;
                rsum[r] += p;
            }
#pragma unroll
        for (int r = 0; r < 4; ++r) {
            rsum[r] += __shfl_xor(rsum[r], 1);
            rsum[r] += __shfl_xor(rsum[r], 2);
            rsum[r] += __shfl_xor(rsum[r], 4);
            rsum[r] += __shfl_xor(rsum[r], 8);
            lrow[r] = lrow[r] * alpha[r] + rsum[r];
        }
#pragma unroll
        for (int ntd = 0; ntd < 4; ++ntd)
#pragma unroll
            for (int r = 0; r < 4; ++r) o[ntd][r] *= alpha[r];

#pragma unroll
        for (int nt = 0; nt < 4; ++nt)
#pragma unroll
            for (int r = 0; r < 4; ++r)
                Ps[w][quad * 4 + r][nt * 16 + ln] = f2bf(s[nt][r]);
        asm volatile("s_waitcnt lgkmcnt(0)" ::: "memory");

        const s16x8 aP0 = *(const s16x8*)&Ps[w][ln][quad * 8];
        const s16x8 aP1 = *(const s16x8*)&Ps[w][ln][32 + quad * 8];
#pragma unroll
        for (int ntd = 0; ntd < 4; ++ntd) {
            const s16x8 b0 = *(const s16x8*)&Vt[ntd * 16 + ln][quad * 8];
            const s16x8 b1 = *(const s16x8*)&Vt[ntd * 16 + ln][32 + quad * 8];
            o[ntd] = __builtin_amdgcn_mfma_f32_16x16x32_bf16(aP0, b0, o[ntd], 0, 0, 0);
            o[ntd] = __builtin_amdgcn_mfma_f32_16x16x32_bf16(aP1, b1, o[ntd], 0, 0, 0);
        }
    }

    float invl[4];
#pragma unroll
    for (int r = 0; r < 4; ++r) invl[r] = 1.f / lrow[r];
#pragma unroll
    for (int ntd = 0; ntd < 4; ++ntd)
#pragma unroll
        for (int r = 0; r < 4; ++r) {
            const size_t row = (size_t)(b * NQ + qt * 64 + w * 16 + quad * 4 + r);
            Z[row * EMB + h * HD + ntd * 16 + ln] = f2bf(o[ntd][r] * invl[r]);
        }
}

extern "C" void kernel_launch(void* const* d_in, const int* in_sizes, int n_in,
                              void* d_out, int out_size, void* d_ws, size_t ws_size,
                              hipStream_t stream) {
    const float* x  = (const float*)d_in[0];
    const float* Wq = (const float*)d_in[1];
    const float* Wk = (const float*)d_in[2];
    const float* Wv = (const float*)d_in[3];
    const float* Wo = (const float*)d_in[4];
    const float* bo = (const float*)d_in[5];
    float* out = (float*)d_out;

    const int M = BATCH * NQ;                                   // 4096
    char* ws = (char*)d_ws;
    ushort_t* xb     = (ushort_t*)ws;                           //  8.00 MB
    ushort_t* Wqkv_t = (ushort_t*)(ws + (size_t)(8) * 1024 * 1024);        // 2.25 MB
    ushort_t* Wo_t   = (ushort_t*)(ws + (size_t)(8 + 3) * 1024 * 1024);    // 2.00 MB
    ushort_t* QKV    = (ushort_t*)(ws + (size_t)(8 + 5) * 1024 * 1024);    // 9.00 MB
    ushort_t* Zb     = (ushort_t*)(ws + (size_t)(8 + 15) * 1024 * 1024);   // 8.00 MB

    dim3 blk(256);
    convert_bf16<<<dim3(M * EMB / 1024), blk, 0, stream>>>(x, xb);
    transpose_bf16<<<dim3(32, 32), blk, 0, stream>>>(Wq, Wqkv_t, EMB, EMB, EMB);
    transpose_bf16<<<dim3(2,  32), blk, 0, stream>>>(Wk, Wqkv_t + (size_t)1024 * EMB, EMB, HD, EMB);
    transpose_bf16<<<dim3(2,  32), blk, 0, stream>>>(Wv, Wqkv_t + (size_t)1088 * EMB, EMB, HD, EMB);
    transpose_bf16<<<dim3(32, 32), blk, 0, stream>>>(Wo, Wo_t, EMB, EMB, EMB);

    gemm_bf16<false, ushort_t><<<dim3(NKV / 128, M / 128), blk, 0, stream>>>(
        xb, Wqkv_t, nullptr, QKV, M, NKV, EMB);
    attn_mfma<<<dim3(NQ / 64, HEADS, BATCH), blk, 0, stream>>>(QKV, Zb);
    gemm_bf16<true, float><<<dim3(EMB / 128, M / 128), blk, 0, stream>>>(
        Zb, Wo_t, bo, out, M, EMB, EMB);
}

// Round 4
// 213.713 us; speedup vs baseline: 10.6974x; 1.2947x over previous
//
#include <hip/hip_runtime.h>
#include <hip/hip_bf16.h>

// B=2, N=2048, E=1024, H=16, D=64 (MQA). out = softmax(causal(QK^T/8)) V @ Wo + bo
//
// Round 4: attention restructured.
//   - 512 uniform blocks: (b, h, pair p) -> q-tiles {31-p, p}, exactly 33 K-tile
//     iters per block (perfect balance).
//   - K and pre-transposed V staged with global_load_lds w=16, XOR chunk swizzle
//     (chunk ^= row&7), double-buffered: prefetch jt+1 at iter top, one barrier
//     per iter at the end -> global latency hidden behind MFMA+softmax.
//   - transpose_v: QKV's V columns -> Vt[b][d][n] once (so PV B-fragments are
//     k(=key)-contiguous in LDS with no per-iter scalar transpose).

#define NQ 2048
#define BATCH 2
#define HEADS 16
#define HD 64
#define EMB 1024
#define NKV 1152   // 1024 Q cols + 64 K + 64 V

typedef short s16x8 __attribute__((ext_vector_type(8)));
typedef float f32x4 __attribute__((ext_vector_type(4)));
typedef unsigned short ushort_t;

__device__ __forceinline__ ushort_t f2bf(float f) {
    unsigned u = __builtin_bit_cast(unsigned, f);
    u += 0x7fff + ((u >> 16) & 1);          // RNE
    return (ushort_t)(u >> 16);
}

__device__ __forceinline__ void store_out(float* p, float v) { *p = v; }
__device__ __forceinline__ void store_out(ushort_t* p, float v) { *p = f2bf(v); }

// async global->LDS, 16B per lane. LDS dest = wave-uniform base + lane*16.
#define GL16(g, l)                                                                  \
    __builtin_amdgcn_global_load_lds(                                               \
        (const __attribute__((address_space(1))) unsigned int*)(g),                 \
        (__attribute__((address_space(3))) unsigned int*)(l), 16, 0, 0)

__global__ void convert_bf16(const float* __restrict__ src, ushort_t* __restrict__ dst) {
    const int i = (blockIdx.x * 256 + threadIdx.x) * 4;
    const float4 v = *(const float4*)&src[i];
    ushort_t o[4] = {f2bf(v.x), f2bf(v.y), f2bf(v.z), f2bf(v.w)};
    *(uint2*)&dst[i] = *(uint2*)o;
}

// dst[n][k] = src[k][n] (fp32 -> bf16). src: K x N row-major; dst row stride = dstride.
__global__ void transpose_bf16(const float* __restrict__ src, ushort_t* __restrict__ dst,
                               int K, int N, int dstride) {
    __shared__ float tile[32][33];
    const int k0 = blockIdx.y * 32, n0 = blockIdx.x * 32;
    const int tx = threadIdx.x & 31, ty = threadIdx.x >> 5;
#pragma unroll
    for (int i = 0; i < 32; i += 8)
        tile[ty + i][tx] = src[(size_t)(k0 + ty + i) * N + n0 + tx];
    __syncthreads();
#pragma unroll
    for (int i = 0; i < 32; i += 8)
        dst[(size_t)(n0 + ty + i) * dstride + k0 + tx] = f2bf(tile[tx][ty + i]);
}

// Vt[b][d][n] = V[b][n][d]; V lives in QKV packed at col 1088. 64 blocks x 64 rows.
__global__ __launch_bounds__(256) void transpose_v(const ushort_t* __restrict__ QKV,
                                                   ushort_t* __restrict__ Vt) {
    const int blk = blockIdx.x;
    const int b = blk >> 5, n0 = (blk & 31) * 64;
    __shared__ ushort_t tl[64][72];
    const int t = threadIdx.x;
#pragma unroll
    for (int it = 0; it < 2; ++it) {
        const int idx = t + it * 256;
        const int r = idx >> 3, c = (idx & 7) * 8;
        *(uint4*)&tl[r][c] =
            *(const uint4*)&QKV[(size_t)(b * NQ + n0 + r) * NKV + 1088 + c];
    }
    __syncthreads();
#pragma unroll
    for (int it = 0; it < 2; ++it) {
        const int idx = t + it * 256;
        const int d = idx >> 3, c = (idx & 7) * 8;
        ushort_t tmp[8];
#pragma unroll
        for (int j = 0; j < 8; ++j) tmp[j] = tl[c + j][d];
        *(uint4*)&Vt[(size_t)(b * 64 + d) * NQ + n0 + c] = *(uint4*)&tmp[0];
    }
}

// bf16 MFMA GEMM: C(M,N) = A(M,K) @ Bt(N,K)^T [+ bias]. (unchanged from round 3)
template<bool HAS_BIAS, typename OutT>
__global__ __launch_bounds__(256) void gemm_bf16(const ushort_t* __restrict__ A,
                                                 const ushort_t* __restrict__ Bt,
                                                 const float* __restrict__ bias,
                                                 OutT* __restrict__ C,
                                                 int M, int N, int K) {
    __shared__ __align__(16) ushort_t Al[128 * 32];
    __shared__ __align__(16) ushort_t Bl[128 * 32];
    const int t = threadIdx.x;
    const int w = t >> 6, lane = t & 63, quad = lane >> 4, ln = lane & 15;
    const int wm = w >> 1, wn = w & 1;
    const int row0 = blockIdx.y * 128, col0 = blockIdx.x * 128;

    const int r0 = t >> 2, r1 = (t + 256) >> 2;
    const int lc0 = (t & 3) ^ ((r0 >> 1) & 3);
    const int lc1 = (t & 3) ^ ((r1 >> 1) & 3);
    const ushort_t* ga0 = A + (size_t)(row0 + r0) * K + lc0 * 8;
    const ushort_t* ga1 = A + (size_t)(row0 + r1) * K + lc1 * 8;
    const ushort_t* gb0 = Bt + (size_t)(col0 + r0) * K + lc0 * 8;
    const ushort_t* gb1 = Bt + (size_t)(col0 + r1) * K + lc1 * 8;
    ushort_t* lA0 = Al + w * 512;
    ushort_t* lA1 = Al + 2048 + w * 512;
    ushort_t* lB0 = Bl + w * 512;
    ushort_t* lB1 = Bl + 2048 + w * 512;

    f32x4 acc[4][4] = {};
    const int sw = (ln >> 1) & 3;
    for (int k0 = 0; k0 < K; k0 += 32) {
        GL16(ga0, lA0); GL16(ga1, lA1);
        GL16(gb0, lB0); GL16(gb1, lB1);
        ga0 += 32; ga1 += 32; gb0 += 32; gb1 += 32;
        __syncthreads();

        s16x8 af[4], bf[4];
#pragma unroll
        for (int mt = 0; mt < 4; ++mt) {
            const int r = wm * 64 + mt * 16 + ln;
            af[mt] = *(const s16x8*)&Al[r * 32 + ((quad ^ sw) * 8)];
        }
#pragma unroll
        for (int nt = 0; nt < 4; ++nt) {
            const int r = wn * 64 + nt * 16 + ln;
            bf[nt] = *(const s16x8*)&Bl[r * 32 + ((quad ^ sw) * 8)];
        }
#pragma unroll
        for (int mt = 0; mt < 4; ++mt)
#pragma unroll
            for (int nt = 0; nt < 4; ++nt)
                acc[mt][nt] = __builtin_amdgcn_mfma_f32_16x16x32_bf16(
                    af[mt], bf[nt], acc[mt][nt], 0, 0, 0);
        __syncthreads();
    }

#pragma unroll
    for (int nt = 0; nt < 4; ++nt) {
        const int col = col0 + wn * 64 + nt * 16 + ln;
        const float bv = HAS_BIAS ? bias[col] : 0.f;
#pragma unroll
        for (int mt = 0; mt < 4; ++mt)
#pragma unroll
            for (int r = 0; r < 4; ++r) {
                const int row = row0 + wm * 64 + mt * 16 + quad * 4 + r;
                store_out(&C[(size_t)row * N + col], acc[mt][nt][r] + bv);
            }
    }
}

// ---- attention helpers: 64x64 bf16 tile in LDS, [row][chunk], chunk = 16B of
// the inner dim; physical chunk = logical ^ (row&7). ----
__device__ __forceinline__ void stage_tile(ushort_t* lds, const ushort_t* g,
                                           size_t rstride, int w, int lane) {
#pragma unroll
    for (int it = 0; it < 2; ++it) {
        const int u = (w * 2 + it) * 64 + lane;
        const int row = u >> 3, pc = u & 7;
        const int lc = pc ^ (row & 7);
        GL16(g + (size_t)row * rstride + lc * 8, lds + (size_t)(w * 2 + it) * 512);
    }
}

__device__ __forceinline__ s16x8 frag(const ushort_t* lds, int row, int lc) {
    const int phys = lc ^ (row & 7);
    return *(const s16x8*)&lds[row * 64 + phys * 8];
}

// Flash attention. grid = 512 blocks: b = bid>>8, h = (bid>>4)&15, p = bid&15;
// block handles q-tiles {31-p, p} (33 iters total). 4 waves x 16 query rows.
__global__ __launch_bounds__(256) void attn_mfma(const ushort_t* __restrict__ QKV,
                                                 const ushort_t* __restrict__ Vt,
                                                 ushort_t* __restrict__ Z) {
    const int bid = blockIdx.x;
    const int b = bid >> 8, h = (bid >> 4) & 15, p = bid & 15;
    const int t = threadIdx.x;
    const int w = t >> 6, lane = t & 63, quad = lane >> 4, ln = lane & 15;

    __shared__ __align__(16) ushort_t Qs[64 * 64];
    __shared__ __align__(16) ushort_t Kl[2][64 * 64];
    __shared__ __align__(16) ushort_t Vl[2][64 * 64];
    __shared__ __align__(16) ushort_t Ps[4][16][72];

    const ushort_t* Kg = QKV + (size_t)b * NQ * NKV + 1024;   // + key*NKV
    const ushort_t* Vg = Vt + (size_t)b * 64 * NQ;            // + d*NQ + key

#pragma unroll 1
    for (int ph = 0; ph < 2; ++ph) {
        const int qt = ph ? p : 31 - p;

        stage_tile(Qs, QKV + (size_t)(b * NQ + qt * 64) * NKV + h * HD, NKV, w, lane);
        stage_tile(Kl[0], Kg, NKV, w, lane);
        stage_tile(Vl[0], Vg, NQ, w, lane);
        __syncthreads();   // drains vmcnt -> Q, K0, V0 ready

        const s16x8 aQ0 = frag(Qs, w * 16 + ln, quad);
        const s16x8 aQ1 = frag(Qs, w * 16 + ln, 4 + quad);

        f32x4 o[4];
#pragma unroll
        for (int i = 0; i < 4; ++i) o[i] = f32x4{0.f, 0.f, 0.f, 0.f};
        float mrow[4], lrow[4];
#pragma unroll
        for (int r = 0; r < 4; ++r) { mrow[r] = -1e30f; lrow[r] = 0.f; }

#pragma unroll 1
        for (int jt = 0; jt <= qt; ++jt) {
            const int cur = jt & 1;
            if (jt < qt) {   // prefetch next tiles; drained by end-of-iter barrier
                stage_tile(Kl[cur ^ 1], Kg + (size_t)(jt + 1) * 64 * NKV, NKV, w, lane);
                stage_tile(Vl[cur ^ 1], Vg + (jt + 1) * 64, NQ, w, lane);
            }
            const ushort_t* Kc = Kl[cur];
            const ushort_t* Vc = Vl[cur];

            // S = Q K^T
            f32x4 s[4];
#pragma unroll
            for (int nt = 0; nt < 4; ++nt) {
                f32x4 acc = f32x4{0.f, 0.f, 0.f, 0.f};
                const s16x8 b0 = frag(Kc, nt * 16 + ln, quad);
                const s16x8 b1 = frag(Kc, nt * 16 + ln, 4 + quad);
                acc = __builtin_amdgcn_mfma_f32_16x16x32_bf16(aQ0, b0, acc, 0, 0, 0);
                acc = __builtin_amdgcn_mfma_f32_16x16x32_bf16(aQ1, b1, acc, 0, 0, 0);
                s[nt] = acc;
            }

            // scale + causal mask + online softmax (rows w*16 + quad*4 + r)
            const bool diag = (jt == qt);
            float rmax[4];
#pragma unroll
            for (int r = 0; r < 4; ++r) rmax[r] = -1e30f;
#pragma unroll
            for (int nt = 0; nt < 4; ++nt)
#pragma unroll
                for (int r = 0; r < 4; ++r) {
                    float v = s[nt][r] * 0.125f;
                    if (diag && (nt * 16 + ln) > (w * 16 + quad * 4 + r)) v = -1e30f;
                    s[nt][r] = v;
                    rmax[r] = fmaxf(rmax[r], v);
                }
#pragma unroll
            for (int r = 0; r < 4; ++r) {
                rmax[r] = fmaxf(rmax[r], __shfl_xor(rmax[r], 1));
                rmax[r] = fmaxf(rmax[r], __shfl_xor(rmax[r], 2));
                rmax[r] = fmaxf(rmax[r], __shfl_xor(rmax[r], 4));
                rmax[r] = fmaxf(rmax[r], __shfl_xor(rmax[r], 8));
            }
            float alpha[4], rsum[4];
#pragma unroll
            for (int r = 0; r < 4; ++r) {
                const float mnew = fmaxf(mrow[r], rmax[r]);
                alpha[r] = __expf(mrow[r] - mnew);
                mrow[r] = mnew;
                rsum[r] = 0.f;
            }
#pragma unroll
            for (int nt = 0; nt < 4; ++nt)
#pragma unroll
                for (int r = 0; r < 4; ++r) {
                    const float pv = __expf(s[nt][r] - mrow[r]);
                    s[nt][r] = pv;
                    rsum[r] += pv;
                }
#pragma unroll
            for (int r = 0; r < 4; ++r) {
                rsum[r] += __shfl_xor(rsum[r], 1);
                rsum[r] += __shfl_xor(rsum[r], 2);
                rsum[r] += __shfl_xor(rsum[r], 4);
                rsum[r] += __shfl_xor(rsum[r], 8);
                lrow[r] = lrow[r] * alpha[r] + rsum[r];
            }
#pragma unroll
            for (int ntd = 0; ntd < 4; ++ntd)
#pragma unroll
                for (int r = 0; r < 4; ++r) o[ntd][r] *= alpha[r];

            // P -> per-wave LDS (C-layout), re-read in A-layout (in-wave fence only)
#pragma unroll
            for (int nt = 0; nt < 4; ++nt)
#pragma unroll
                for (int r = 0; r < 4; ++r)
                    Ps[w][quad * 4 + r][nt * 16 + ln] = f2bf(s[nt][r]);
            asm volatile("s_waitcnt lgkmcnt(0)" ::: "memory");

            const s16x8 aP0 = *(const s16x8*)&Ps[w][ln][quad * 8];
            const s16x8 aP1 = *(const s16x8*)&Ps[w][ln][32 + quad * 8];
#pragma unroll
            for (int ntd = 0; ntd < 4; ++ntd) {
                const s16x8 b0 = frag(Vc, ntd * 16 + ln, quad);
                const s16x8 b1 = frag(Vc, ntd * 16 + ln, 4 + quad);
                o[ntd] = __builtin_amdgcn_mfma_f32_16x16x32_bf16(aP0, b0, o[ntd], 0, 0, 0);
                o[ntd] = __builtin_amdgcn_mfma_f32_16x16x32_bf16(aP1, b1, o[ntd], 0, 0, 0);
            }
            __syncthreads();   // buffer handoff + drains prefetch for next iter
        }

        // epilogue: normalize + store Z (bf16)
        float invl[4];
#pragma unroll
        for (int r = 0; r < 4; ++r) invl[r] = 1.f / lrow[r];
#pragma unroll
        for (int ntd = 0; ntd < 4; ++ntd)
#pragma unroll
            for (int r = 0; r < 4; ++r) {
                const size_t row = (size_t)(b * NQ + qt * 64 + w * 16 + quad * 4 + r);
                Z[row * EMB + h * HD + ntd * 16 + ln] = f2bf(o[ntd][r] * invl[r]);
            }
    }
}

extern "C" void kernel_launch(void* const* d_in, const int* in_sizes, int n_in,
                              void* d_out, int out_size, void* d_ws, size_t ws_size,
                              hipStream_t stream) {
    const float* x  = (const float*)d_in[0];
    const float* Wq = (const float*)d_in[1];
    const float* Wk = (const float*)d_in[2];
    const float* Wv = (const float*)d_in[3];
    const float* Wo = (const float*)d_in[4];
    const float* bo = (const float*)d_in[5];
    float* out = (float*)d_out;

    const int M = BATCH * NQ;                                   // 4096
    char* ws = (char*)d_ws;
    ushort_t* xb     = (ushort_t*)ws;                                      // 8 MB
    ushort_t* Wqkv_t = (ushort_t*)(ws + (size_t)8  * 1024 * 1024);         // 2.25 MB
    ushort_t* Wo_t   = (ushort_t*)(ws + (size_t)11 * 1024 * 1024);         // 2 MB
    ushort_t* QKV    = (ushort_t*)(ws + (size_t)13 * 1024 * 1024);         // 9.22 MB
    ushort_t* Vt     = (ushort_t*)(ws + (size_t)23 * 1024 * 1024);         // 0.5 MB
    ushort_t* Zb     = (ushort_t*)(ws + (size_t)24 * 1024 * 1024);         // 8 MB

    dim3 blk(256);
    convert_bf16<<<dim3(M * EMB / 1024), blk, 0, stream>>>(x, xb);
    transpose_bf16<<<dim3(32, 32), blk, 0, stream>>>(Wq, Wqkv_t, EMB, EMB, EMB);
    transpose_bf16<<<dim3(2,  32), blk, 0, stream>>>(Wk, Wqkv_t + (size_t)1024 * EMB, EMB, HD, EMB);
    transpose_bf16<<<dim3(2,  32), blk, 0, stream>>>(Wv, Wqkv_t + (size_t)1088 * EMB, EMB, HD, EMB);
    transpose_bf16<<<dim3(32, 32), blk, 0, stream>>>(Wo, Wo_t, EMB, EMB, EMB);

    gemm_bf16<false, ushort_t><<<dim3(NKV / 128, M / 128), blk, 0, stream>>>(
        xb, Wqkv_t, nullptr, QKV, M, NKV, EMB);
    transpose_v<<<dim3(64), blk, 0, stream>>>(QKV, Vt);
    attn_mfma<<<dim3(512), blk, 0, stream>>>(QKV, Vt, Zb);
    gemm_bf16<true, float><<<dim3(EMB / 128, M / 128), blk, 0, stream>>>(
        Zb, Wo_t, bo, out, M, EMB, EMB);
}

// Round 7
// 197.680 us; speedup vs baseline: 11.5650x; 1.0811x over previous
//
#include <hip/hip_runtime.h>
#include <hip/hip_bf16.h>

// B=2, N=2048, E=1024, H=16, D=64 (MQA). out = softmax(causal(QK^T/8)) V @ Wo + bo
//
// Round 7 (bisection): attention = VERBATIM round-4 body (proven correct);
// GEMMs/prep = round-5 64x128 tiles + fused prep (audited clean, under test).
// SCALE_Q disabled (round-4 attn applies 0.125 internally).

#define NQ 2048
#define BATCH 2
#define HEADS 16
#define HD 64
#define EMB 1024
#define NKV 1152   // 1024 Q cols + 64 K + 64 V

typedef short s16x8 __attribute__((ext_vector_type(8)));
typedef float f32x4 __attribute__((ext_vector_type(4)));
typedef unsigned short ushort_t;

__device__ __forceinline__ ushort_t f2bf(float f) {
    unsigned u = __builtin_bit_cast(unsigned, f);
    u += 0x7fff + ((u >> 16) & 1);          // RNE
    return (ushort_t)(u >> 16);
}

__device__ __forceinline__ void store_out(float* p, float v) { *p = v; }
__device__ __forceinline__ void store_out(ushort_t* p, float v) { *p = f2bf(v); }

// async global->LDS, 16B per lane. LDS dest = wave-uniform base + lane*16.
#define GL16(g, l)                                                                  \
    __builtin_amdgcn_global_load_lds(                                               \
        (const __attribute__((address_space(1))) unsigned int*)(g),                 \
        (__attribute__((address_space(3))) unsigned int*)(l), 16, 0, 0)

// Fused prep: blocks [0,4096): x fp32->bf16. Blocks [4096,6272): 32x32 transpose
// tiles of Wq/Wk/Wv (packed into Wqkv_t, N-major) and Wo -> Wo_t.
__global__ __launch_bounds__(256) void prep(const float* __restrict__ x,
                                            const float* __restrict__ Wq,
                                            const float* __restrict__ Wk,
                                            const float* __restrict__ Wv,
                                            const float* __restrict__ Wo,
                                            ushort_t* __restrict__ xb,
                                            ushort_t* __restrict__ Wqkv_t,
                                            ushort_t* __restrict__ Wo_t) {
    const int bid = blockIdx.x, t = threadIdx.x;
    if (bid < 4096) {
        const int i = bid * 1024 + t * 4;
        const float4 v = *(const float4*)&x[i];
        ushort_t o[4] = {f2bf(v.x), f2bf(v.y), f2bf(v.z), f2bf(v.w)};
        *(uint2*)&xb[i] = *(uint2*)o;
        return;
    }
    int tb = bid - 4096;
    const float* src; ushort_t* dst; int N, n0, k0;
    if (tb < 1024)      { src = Wq; N = 1024; dst = Wqkv_t;
                          n0 = (tb & 31) * 32; k0 = (tb >> 5) * 32; }
    else if (tb < 1088) { tb -= 1024; src = Wk; N = 64; dst = Wqkv_t + (size_t)1024 * EMB;
                          n0 = (tb & 1) * 32; k0 = (tb >> 1) * 32; }
    else if (tb < 1152) { tb -= 1088; src = Wv; N = 64; dst = Wqkv_t + (size_t)1088 * EMB;
                          n0 = (tb & 1) * 32; k0 = (tb >> 1) * 32; }
    else                { tb -= 1152; src = Wo; N = 1024; dst = Wo_t;
                          n0 = (tb & 31) * 32; k0 = (tb >> 5) * 32; }
    __shared__ float tile[32][33];
    const int tx = t & 31, ty = t >> 5;
#pragma unroll
    for (int i = 0; i < 32; i += 8)
        tile[ty + i][tx] = src[(size_t)(k0 + ty + i) * N + n0 + tx];
    __syncthreads();
#pragma unroll
    for (int i = 0; i < 32; i += 8)
        dst[(size_t)(n0 + ty + i) * EMB + k0 + tx] = f2bf(tile[tx][ty + i]);
}

// Vt[b][d][n] = V[b][n][d]; V lives in QKV packed at col 1088.
__global__ __launch_bounds__(256) void transpose_v(const ushort_t* __restrict__ QKV,
                                                   ushort_t* __restrict__ Vt) {
    const int blk = blockIdx.x;
    const int b = blk >> 5, n0 = (blk & 31) * 64;
    __shared__ ushort_t tl[64][72];
    const int t = threadIdx.x;
#pragma unroll
    for (int it = 0; it < 2; ++it) {
        const int idx = t + it * 256;
        const int r = idx >> 3, c = (idx & 7) * 8;
        *(uint4*)&tl[r][c] =
            *(const uint4*)&QKV[(size_t)(b * NQ + n0 + r) * NKV + 1088 + c];
    }
    __syncthreads();
#pragma unroll
    for (int it = 0; it < 2; ++it) {
        const int idx = t + it * 256;
        const int d = idx >> 3, c = (idx & 7) * 8;
        ushort_t tmp[8];
#pragma unroll
        for (int j = 0; j < 8; ++j) tmp[j] = tl[c + j][d];
        *(uint4*)&Vt[(size_t)(b * 64 + d) * NQ + n0 + c] = *(uint4*)&tmp[0];
    }
}

// bf16 MFMA GEMM: C(M,N) = A(M,K) @ Bt(N,K)^T [+ bias]. 64x128 tile, BK=32.
template<bool HAS_BIAS, bool SCALE_Q, typename OutT>
__global__ __launch_bounds__(256) void gemm_bf16(const ushort_t* __restrict__ A,
                                                 const ushort_t* __restrict__ Bt,
                                                 const float* __restrict__ bias,
                                                 OutT* __restrict__ C,
                                                 int M, int N, int K) {
    __shared__ __align__(16) ushort_t Al[64 * 32];
    __shared__ __align__(16) ushort_t Bl[128 * 32];
    const int t = threadIdx.x;
    const int w = t >> 6, lane = t & 63, quad = lane >> 4, ln = lane & 15;
    const int row0 = blockIdx.y * 64, col0 = blockIdx.x * 128;

    const int rA = t >> 2;
    const int lcA = (t & 3) ^ ((rA >> 1) & 3);
    const int rB1 = 64 + rA;
    const ushort_t* ga  = A  + (size_t)(row0 + rA) * K + lcA * 8;
    const ushort_t* gb0 = Bt + (size_t)(col0 + rA) * K + lcA * 8;
    const ushort_t* gb1 = Bt + (size_t)(col0 + rB1) * K + lcA * 8;
    ushort_t* lA  = Al + w * 512;
    ushort_t* lB0 = Bl + w * 512;
    ushort_t* lB1 = Bl + 2048 + w * 512;

    f32x4 acc[4][2] = {};
    const int sw = (ln >> 1) & 3;
    for (int k0 = 0; k0 < K; k0 += 32) {
        GL16(ga, lA); GL16(gb0, lB0); GL16(gb1, lB1);
        ga += 32; gb0 += 32; gb1 += 32;
        __syncthreads();

        s16x8 af[4], bf[2];
#pragma unroll
        for (int mt = 0; mt < 4; ++mt)
            af[mt] = *(const s16x8*)&Al[(mt * 16 + ln) * 32 + ((quad ^ sw) * 8)];
#pragma unroll
        for (int nt = 0; nt < 2; ++nt)
            bf[nt] = *(const s16x8*)&Bl[(w * 32 + nt * 16 + ln) * 32 + ((quad ^ sw) * 8)];
#pragma unroll
        for (int mt = 0; mt < 4; ++mt)
#pragma unroll
            for (int nt = 0; nt < 2; ++nt)
                acc[mt][nt] = __builtin_amdgcn_mfma_f32_16x16x32_bf16(
                    af[mt], bf[nt], acc[mt][nt], 0, 0, 0);
        __syncthreads();
    }

#pragma unroll
    for (int nt = 0; nt < 2; ++nt) {
        const int col = col0 + w * 32 + nt * 16 + ln;
        const float bv = HAS_BIAS ? bias[col] : 0.f;
        const float sc = (SCALE_Q && col < 1024) ? 0.18033688f : 1.f;
#pragma unroll
        for (int mt = 0; mt < 4; ++mt)
#pragma unroll
            for (int r = 0; r < 4; ++r) {
                const int row = row0 + mt * 16 + quad * 4 + r;
                store_out(&C[(size_t)row * N + col], acc[mt][nt][r] * sc + bv);
            }
    }
}

// ---- attention LDS helpers (shared by round-4 attn): 64x64 bf16 tile,
// [row][chunk], chunk=16B of inner dim; physical chunk = logical ^ (row&7). ----
__device__ __forceinline__ void stage_tile(ushort_t* lds, const ushort_t* g,
                                           size_t rstride, int w, int lane) {
#pragma unroll
    for (int it = 0; it < 2; ++it) {
        const int u = (w * 2 + it) * 64 + lane;
        const int row = u >> 3, pc = u & 7;
        const int lc = pc ^ (row & 7);
        GL16(g + (size_t)row * rstride + lc * 8, lds + (size_t)(w * 2 + it) * 512);
    }
}

__device__ __forceinline__ s16x8 frag(const ushort_t* lds, int row, int lc) {
    const int phys = lc ^ (row & 7);
    return *(const s16x8*)&lds[row * 64 + phys * 8];
}

// ===== VERBATIM round-4 attention (proven): 512 blocks, q-tile pairs {31-p, p},
// running-max online softmax, separate Ps buffer, __expf, 0.125 in-kernel. =====
__global__ __launch_bounds__(256) void attn_mfma(const ushort_t* __restrict__ QKV,
                                                 const ushort_t* __restrict__ Vt,
                                                 ushort_t* __restrict__ Z) {
    const int bid = blockIdx.x;
    const int b = bid >> 8, h = (bid >> 4) & 15, p = bid & 15;
    const int t = threadIdx.x;
    const int w = t >> 6, lane = t & 63, quad = lane >> 4, ln = lane & 15;

    __shared__ __align__(16) ushort_t Qs[64 * 64];
    __shared__ __align__(16) ushort_t Kl[2][64 * 64];
    __shared__ __align__(16) ushort_t Vl[2][64 * 64];
    __shared__ __align__(16) ushort_t Ps[4][16][72];

    const ushort_t* Kg = QKV + (size_t)b * NQ * NKV + 1024;   // + key*NKV
    const ushort_t* Vg = Vt + (size_t)b * 64 * NQ;            // + d*NQ + key

#pragma unroll 1
    for (int ph = 0; ph < 2; ++ph) {
        const int qt = ph ? p : 31 - p;

        stage_tile(Qs, QKV + (size_t)(b * NQ + qt * 64) * NKV + h * HD, NKV, w, lane);
        stage_tile(Kl[0], Kg, NKV, w, lane);
        stage_tile(Vl[0], Vg, NQ, w, lane);
        __syncthreads();   // drains vmcnt -> Q, K0, V0 ready

        const s16x8 aQ0 = frag(Qs, w * 16 + ln, quad);
        const s16x8 aQ1 = frag(Qs, w * 16 + ln, 4 + quad);

        f32x4 o[4];
#pragma unroll
        for (int i = 0; i < 4; ++i) o[i] = f32x4{0.f, 0.f, 0.f, 0.f};
        float mrow[4], lrow[4];
#pragma unroll
        for (int r = 0; r < 4; ++r) { mrow[r] = -1e30f; lrow[r] = 0.f; }

#pragma unroll 1
        for (int jt = 0; jt <= qt; ++jt) {
            const int cur = jt & 1;
            if (jt < qt) {   // prefetch next tiles; drained by end-of-iter barrier
                stage_tile(Kl[cur ^ 1], Kg + (size_t)(jt + 1) * 64 * NKV, NKV, w, lane);
                stage_tile(Vl[cur ^ 1], Vg + (jt + 1) * 64, NQ, w, lane);
            }
            const ushort_t* Kc = Kl[cur];
            const ushort_t* Vc = Vl[cur];

            // S = Q K^T
            f32x4 s[4];
#pragma unroll
            for (int nt = 0; nt < 4; ++nt) {
                f32x4 acc = f32x4{0.f, 0.f, 0.f, 0.f};
                const s16x8 b0 = frag(Kc, nt * 16 + ln, quad);
                const s16x8 b1 = frag(Kc, nt * 16 + ln, 4 + quad);
                acc = __builtin_amdgcn_mfma_f32_16x16x32_bf16(aQ0, b0, acc, 0, 0, 0);
                acc = __builtin_amdgcn_mfma_f32_16x16x32_bf16(aQ1, b1, acc, 0, 0, 0);
                s[nt] = acc;
            }

            // scale + causal mask + online softmax (rows w*16 + quad*4 + r)
            const bool diag = (jt == qt);
            float rmax[4];
#pragma unroll
            for (int r = 0; r < 4; ++r) rmax[r] = -1e30f;
#pragma unroll
            for (int nt = 0; nt < 4; ++nt)
#pragma unroll
                for (int r = 0; r < 4; ++r) {
                    float v = s[nt][r] * 0.125f;
                    if (diag && (nt * 16 + ln) > (w * 16 + quad * 4 + r)) v = -1e30f;
                    s[nt][r] = v;
                    rmax[r] = fmaxf(rmax[r], v);
                }
#pragma unroll
            for (int r = 0; r < 4; ++r) {
                rmax[r] = fmaxf(rmax[r], __shfl_xor(rmax[r], 1));
                rmax[r] = fmaxf(rmax[r], __shfl_xor(rmax[r], 2));
                rmax[r] = fmaxf(rmax[r], __shfl_xor(rmax[r], 4));
                rmax[r] = fmaxf(rmax[r], __shfl_xor(rmax[r], 8));
            }
            float alpha[4], rsum[4];
#pragma unroll
            for (int r = 0; r < 4; ++r) {
                const float mnew = fmaxf(mrow[r], rmax[r]);
                alpha[r] = __expf(mrow[r] - mnew);
                mrow[r] = mnew;
                rsum[r] = 0.f;
            }
#pragma unroll
            for (int nt = 0; nt < 4; ++nt)
#pragma unroll
                for (int r = 0; r < 4; ++r) {
                    const float pv = __expf(s[nt][r] - mrow[r]);
                    s[nt][r] = pv;
                    rsum[r] += pv;
                }
#pragma unroll
            for (int r = 0; r < 4; ++r) {
                rsum[r] += __shfl_xor(rsum[r], 1);
                rsum[r] += __shfl_xor(rsum[r], 2);
                rsum[r] += __shfl_xor(rsum[r], 4);
                rsum[r] += __shfl_xor(rsum[r], 8);
                lrow[r] = lrow[r] * alpha[r] + rsum[r];
            }
#pragma unroll
            for (int ntd = 0; ntd < 4; ++ntd)
#pragma unroll
                for (int r = 0; r < 4; ++r) o[ntd][r] *= alpha[r];

            // P -> per-wave LDS (C-layout), re-read in A-layout (in-wave fence only)
#pragma unroll
            for (int nt = 0; nt < 4; ++nt)
#pragma unroll
                for (int r = 0; r < 4; ++r)
                    Ps[w][quad * 4 + r][nt * 16 + ln] = f2bf(s[nt][r]);
            asm volatile("s_waitcnt lgkmcnt(0)" ::: "memory");

            const s16x8 aP0 = *(const s16x8*)&Ps[w][ln][quad * 8];
            const s16x8 aP1 = *(const s16x8*)&Ps[w][ln][32 + quad * 8];
#pragma unroll
            for (int ntd = 0; ntd < 4; ++ntd) {
                const s16x8 b0 = frag(Vc, ntd * 16 + ln, quad);
                const s16x8 b1 = frag(Vc, ntd * 16 + ln, 4 + quad);
                o[ntd] = __builtin_amdgcn_mfma_f32_16x16x32_bf16(aP0, b0, o[ntd], 0, 0, 0);
                o[ntd] = __builtin_amdgcn_mfma_f32_16x16x32_bf16(aP1, b1, o[ntd], 0, 0, 0);
            }
            __syncthreads();   // buffer handoff + drains prefetch for next iter
        }

        // epilogue: normalize + store Z (bf16)
        float invl[4];
#pragma unroll
        for (int r = 0; r < 4; ++r) invl[r] = 1.f / lrow[r];
#pragma unroll
        for (int ntd = 0; ntd < 4; ++ntd)
#pragma unroll
            for (int r = 0; r < 4; ++r) {
                const size_t row = (size_t)(b * NQ + qt * 64 + w * 16 + quad * 4 + r);
                Z[row * EMB + h * HD + ntd * 16 + ln] = f2bf(o[ntd][r] * invl[r]);
            }
    }
}

extern "C" void kernel_launch(void* const* d_in, const int* in_sizes, int n_in,
                              void* d_out, int out_size, void* d_ws, size_t ws_size,
                              hipStream_t stream) {
    const float* x  = (const float*)d_in[0];
    const float* Wq = (const float*)d_in[1];
    const float* Wk = (const float*)d_in[2];
    const float* Wv = (const float*)d_in[3];
    const float* Wo = (const float*)d_in[4];
    const float* bo = (const float*)d_in[5];
    float* out = (float*)d_out;

    const int M = BATCH * NQ;                                   // 4096
    char* ws = (char*)d_ws;
    ushort_t* xb     = (ushort_t*)ws;                                      // 8 MB
    ushort_t* Wqkv_t = (ushort_t*)(ws + (size_t)8  * 1024 * 1024);         // 2.25 MB
    ushort_t* Wo_t   = (ushort_t*)(ws + (size_t)11 * 1024 * 1024);         // 2 MB
    ushort_t* QKV    = (ushort_t*)(ws + (size_t)13 * 1024 * 1024);         // 9.22 MB
    ushort_t* Vt     = (ushort_t*)(ws + (size_t)23 * 1024 * 1024);         // 0.5 MB
    ushort_t* Zb     = (ushort_t*)(ws + (size_t)24 * 1024 * 1024);         // 8 MB

    dim3 blk(256);
    prep<<<dim3(6272), blk, 0, stream>>>(x, Wq, Wk, Wv, Wo, xb, Wqkv_t, Wo_t);
    gemm_bf16<false, false, ushort_t><<<dim3(NKV / 128, M / 64), blk, 0, stream>>>(
        xb, Wqkv_t, nullptr, QKV, M, NKV, EMB);
    transpose_v<<<dim3(64), blk, 0, stream>>>(QKV, Vt);
    attn_mfma<<<dim3(512), blk, 0, stream>>>(QKV, Vt, Zb);
    gemm_bf16<true, false, float><<<dim3(EMB / 128, M / 64), blk, 0, stream>>>(
        Zb, Wo_t, bo, out, M, EMB, EMB);
}

// Round 9
// 188.643 us; speedup vs baseline: 12.1190x; 1.0479x over previous
//
#include <hip/hip_runtime.h>
#include <hip/hip_bf16.h>

// B=2, N=2048, E=1024, H=16, D=64 (MQA). out = softmax(causal(QK^T/8)) V @ Wo + bo
//
// Round 9: occupancy + dispatch-count attack; softmax math untouched (round-7 proven).
//   - attn: 1024 blocks (one q-tile each), qt swizzle makes each CU's 4 co-resident
//     blocks sum to 66 iters; P stored into the Q staging buffer (XOR-swizzled
//     layout, per-wave rows) -> 40 KB LDS -> 4 blocks/CU, all blocks resident.
//   - QKV GEMM epilogue writes Vt directly (transpose_v kernel eliminated).
//   - GEMMs/prep: round-7 64x128 + fused prep, unchanged.

#define NQ 2048
#define BATCH 2
#define HEADS 16
#define HD 64
#define EMB 1024
#define NKV 1152   // 1024 Q cols + 64 K + 64 V

typedef short s16x8 __attribute__((ext_vector_type(8)));
typedef float f32x4 __attribute__((ext_vector_type(4)));
typedef unsigned short ushort_t;

__device__ __forceinline__ ushort_t f2bf(float f) {
    unsigned u = __builtin_bit_cast(unsigned, f);
    u += 0x7fff + ((u >> 16) & 1);          // RNE
    return (ushort_t)(u >> 16);
}

__device__ __forceinline__ void store_out(float* p, float v) { *p = v; }
__device__ __forceinline__ void store_out(ushort_t* p, float v) { *p = f2bf(v); }

// async global->LDS, 16B per lane. LDS dest = wave-uniform base + lane*16.
#define GL16(g, l)                                                                  \
    __builtin_amdgcn_global_load_lds(                                               \
        (const __attribute__((address_space(1))) unsigned int*)(g),                 \
        (__attribute__((address_space(3))) unsigned int*)(l), 16, 0, 0)

// Fused prep: blocks [0,4096): x fp32->bf16. Blocks [4096,6272): 32x32 transpose
// tiles of Wq/Wk/Wv (packed into Wqkv_t, N-major) and Wo -> Wo_t.
__global__ __launch_bounds__(256) void prep(const float* __restrict__ x,
                                            const float* __restrict__ Wq,
                                            const float* __restrict__ Wk,
                                            const float* __restrict__ Wv,
                                            const float* __restrict__ Wo,
                                            ushort_t* __restrict__ xb,
                                            ushort_t* __restrict__ Wqkv_t,
                                            ushort_t* __restrict__ Wo_t) {
    const int bid = blockIdx.x, t = threadIdx.x;
    if (bid < 4096) {
        const int i = bid * 1024 + t * 4;
        const float4 v = *(const float4*)&x[i];
        ushort_t o[4] = {f2bf(v.x), f2bf(v.y), f2bf(v.z), f2bf(v.w)};
        *(uint2*)&xb[i] = *(uint2*)o;
        return;
    }
    int tb = bid - 4096;
    const float* src; ushort_t* dst; int N, n0, k0;
    if (tb < 1024)      { src = Wq; N = 1024; dst = Wqkv_t;
                          n0 = (tb & 31) * 32; k0 = (tb >> 5) * 32; }
    else if (tb < 1088) { tb -= 1024; src = Wk; N = 64; dst = Wqkv_t + (size_t)1024 * EMB;
                          n0 = (tb & 1) * 32; k0 = (tb >> 1) * 32; }
    else if (tb < 1152) { tb -= 1088; src = Wv; N = 64; dst = Wqkv_t + (size_t)1088 * EMB;
                          n0 = (tb & 1) * 32; k0 = (tb >> 1) * 32; }
    else                { tb -= 1152; src = Wo; N = 1024; dst = Wo_t;
                          n0 = (tb & 31) * 32; k0 = (tb >> 5) * 32; }
    __shared__ float tile[32][33];
    const int tx = t & 31, ty = t >> 5;
#pragma unroll
    for (int i = 0; i < 32; i += 8)
        tile[ty + i][tx] = src[(size_t)(k0 + ty + i) * N + n0 + tx];
    __syncthreads();
#pragma unroll
    for (int i = 0; i < 32; i += 8)
        dst[(size_t)(n0 + ty + i) * EMB + k0 + tx] = f2bf(tile[tx][ty + i]);
}

// bf16 MFMA GEMM: C(M,N) = A(M,K) @ Bt(N,K)^T [+ bias]. 64x128 tile, BK=32.
// WRITE_VT: cols >= 1088 additionally write transposed bf16 to Vt[b][d][n]
// (4 consecutive rows per lane -> one 8B store).
template<bool HAS_BIAS, bool WRITE_VT, typename OutT>
__global__ __launch_bounds__(256) void gemm_bf16(const ushort_t* __restrict__ A,
                                                 const ushort_t* __restrict__ Bt,
                                                 const float* __restrict__ bias,
                                                 OutT* __restrict__ C,
                                                 ushort_t* __restrict__ Vt,
                                                 int M, int N, int K) {
    __shared__ __align__(16) ushort_t Al[64 * 32];
    __shared__ __align__(16) ushort_t Bl[128 * 32];
    const int t = threadIdx.x;
    const int w = t >> 6, lane = t & 63, quad = lane >> 4, ln = lane & 15;
    const int row0 = blockIdx.y * 64, col0 = blockIdx.x * 128;

    const int rA = t >> 2;
    const int lcA = (t & 3) ^ ((rA >> 1) & 3);
    const int rB1 = 64 + rA;
    const ushort_t* ga  = A  + (size_t)(row0 + rA) * K + lcA * 8;
    const ushort_t* gb0 = Bt + (size_t)(col0 + rA) * K + lcA * 8;
    const ushort_t* gb1 = Bt + (size_t)(col0 + rB1) * K + lcA * 8;
    ushort_t* lA  = Al + w * 512;
    ushort_t* lB0 = Bl + w * 512;
    ushort_t* lB1 = Bl + 2048 + w * 512;

    f32x4 acc[4][2] = {};
    const int sw = (ln >> 1) & 3;
    for (int k0 = 0; k0 < K; k0 += 32) {
        GL16(ga, lA); GL16(gb0, lB0); GL16(gb1, lB1);
        ga += 32; gb0 += 32; gb1 += 32;
        __syncthreads();

        s16x8 af[4], bf[2];
#pragma unroll
        for (int mt = 0; mt < 4; ++mt)
            af[mt] = *(const s16x8*)&Al[(mt * 16 + ln) * 32 + ((quad ^ sw) * 8)];
#pragma unroll
        for (int nt = 0; nt < 2; ++nt)
            bf[nt] = *(const s16x8*)&Bl[(w * 32 + nt * 16 + ln) * 32 + ((quad ^ sw) * 8)];
#pragma unroll
        for (int mt = 0; mt < 4; ++mt)
#pragma unroll
            for (int nt = 0; nt < 2; ++nt)
                acc[mt][nt] = __builtin_amdgcn_mfma_f32_16x16x32_bf16(
                    af[mt], bf[nt], acc[mt][nt], 0, 0, 0);
        __syncthreads();
    }

#pragma unroll
    for (int nt = 0; nt < 2; ++nt) {
        const int col = col0 + w * 32 + nt * 16 + ln;
        const float bv = HAS_BIAS ? bias[col] : 0.f;
#pragma unroll
        for (int mt = 0; mt < 4; ++mt) {
#pragma unroll
            for (int r = 0; r < 4; ++r) {
                const int row = row0 + mt * 16 + quad * 4 + r;
                store_out(&C[(size_t)row * N + col], acc[mt][nt][r] + bv);
            }
            if (WRITE_VT && col >= 1088) {
                const int d = col - 1088;
                const int n = row0 + mt * 16 + quad * 4;   // 4 consecutive rows
                const int bb = n >> 11, nn = n & 2047;
                ushort_t tmp[4] = {f2bf(acc[mt][nt][0]), f2bf(acc[mt][nt][1]),
                                   f2bf(acc[mt][nt][2]), f2bf(acc[mt][nt][3])};
                *(uint2*)&Vt[((size_t)bb * 64 + d) * NQ + nn] = *(uint2*)tmp;
            }
        }
    }
}

// ---- attention LDS helpers: 64x64 bf16 tile, [row][chunk], chunk=16B of inner
// dim; physical chunk = logical ^ (row&7). ----
__device__ __forceinline__ void stage_tile(ushort_t* lds, const ushort_t* g,
                                           size_t rstride, int w, int lane) {
#pragma unroll
    for (int it = 0; it < 2; ++it) {
        const int u = (w * 2 + it) * 64 + lane;
        const int row = u >> 3, pc = u & 7;
        const int lc = pc ^ (row & 7);
        GL16(g + (size_t)row * rstride + lc * 8, lds + (size_t)(w * 2 + it) * 512);
    }
}

__device__ __forceinline__ s16x8 frag(const ushort_t* lds, int row, int lc) {
    const int phys = lc ^ (row & 7);
    return *(const s16x8*)&lds[row * 64 + phys * 8];
}

// Flash attention, round-7 softmax math verbatim. 1024 blocks, one q-tile each:
// bid = i*32 + (b,h); qt(i) chosen so bids congruent mod 256 (the 4 blocks
// co-resident per CU) have qt summing to 62 (66 iters). P is stored into the Q
// staging buffer (Q was fully consumed into registers by the owning wave; each
// wave writes/reads only its own 16 rows -> in-wave DS ordering suffices).
__global__ __launch_bounds__(256, 4) void attn_mfma(const ushort_t* __restrict__ QKV,
                                                    const ushort_t* __restrict__ Vt,
                                                    ushort_t* __restrict__ Z) {
    const int bid = blockIdx.x;
    const int b = (bid >> 4) & 1, h = bid & 15;
    const int i = bid >> 5, k = i >> 3, j = i & 7;
    const int qt = (k == 0) ? 2 * j : (k == 1) ? 31 - 2 * j
                 : (k == 2) ? 2 * j + 1 : 30 - 2 * j;
    const int t = threadIdx.x;
    const int w = t >> 6, lane = t & 63, quad = lane >> 4, ln = lane & 15;

    __shared__ __align__(16) ushort_t QPs[64 * 64];        //  8 KB: Q stage, then P
    __shared__ __align__(16) ushort_t Kl[2][64 * 64];      // 16 KB
    __shared__ __align__(16) ushort_t Vl[2][64 * 64];      // 16 KB -> 40960 B total

    const ushort_t* Kg = QKV + (size_t)b * NQ * NKV + 1024;   // + key*NKV
    const ushort_t* Vg = Vt + (size_t)b * 64 * NQ;            // + d*NQ + key

    stage_tile(QPs, QKV + (size_t)(b * NQ + qt * 64) * NKV + h * HD, NKV, w, lane);
    stage_tile(Kl[0], Kg, NKV, w, lane);
    stage_tile(Vl[0], Vg, NQ, w, lane);
    __syncthreads();   // drains vmcnt -> Q, K0, V0 ready

    const s16x8 aQ0 = frag(QPs, w * 16 + ln, quad);
    const s16x8 aQ1 = frag(QPs, w * 16 + ln, 4 + quad);

    f32x4 o[4];
#pragma unroll
    for (int ii = 0; ii < 4; ++ii) o[ii] = f32x4{0.f, 0.f, 0.f, 0.f};
    float mrow[4], lrow[4];
#pragma unroll
    for (int r = 0; r < 4; ++r) { mrow[r] = -1e30f; lrow[r] = 0.f; }

#pragma unroll 1
    for (int jt = 0; jt <= qt; ++jt) {
        const int cur = jt & 1;
        if (jt < qt) {   // prefetch next tiles; drained by end-of-iter barrier
            stage_tile(Kl[cur ^ 1], Kg + (size_t)(jt + 1) * 64 * NKV, NKV, w, lane);
            stage_tile(Vl[cur ^ 1], Vg + (jt + 1) * 64, NQ, w, lane);
        }
        const ushort_t* Kc = Kl[cur];
        const ushort_t* Vc = Vl[cur];

        // S = Q K^T
        f32x4 s[4];
#pragma unroll
        for (int nt = 0; nt < 4; ++nt) {
            f32x4 acc = f32x4{0.f, 0.f, 0.f, 0.f};
            const s16x8 b0 = frag(Kc, nt * 16 + ln, quad);
            const s16x8 b1 = frag(Kc, nt * 16 + ln, 4 + quad);
            acc = __builtin_amdgcn_mfma_f32_16x16x32_bf16(aQ0, b0, acc, 0, 0, 0);
            acc = __builtin_amdgcn_mfma_f32_16x16x32_bf16(aQ1, b1, acc, 0, 0, 0);
            s[nt] = acc;
        }

        // scale + causal mask + online softmax (rows w*16 + quad*4 + r)
        const bool diag = (jt == qt);
        float rmax[4];
#pragma unroll
        for (int r = 0; r < 4; ++r) rmax[r] = -1e30f;
#pragma unroll
        for (int nt = 0; nt < 4; ++nt)
#pragma unroll
            for (int r = 0; r < 4; ++r) {
                float v = s[nt][r] * 0.125f;
                if (diag && (nt * 16 + ln) > (w * 16 + quad * 4 + r)) v = -1e30f;
                s[nt][r] = v;
                rmax[r] = fmaxf(rmax[r], v);
            }
#pragma unroll
        for (int r = 0; r < 4; ++r) {
            rmax[r] = fmaxf(rmax[r], __shfl_xor(rmax[r], 1));
            rmax[r] = fmaxf(rmax[r], __shfl_xor(rmax[r], 2));
            rmax[r] = fmaxf(rmax[r], __shfl_xor(rmax[r], 4));
            rmax[r] = fmaxf(rmax[r], __shfl_xor(rmax[r], 8));
        }
        float alpha[4], rsum[4];
#pragma unroll
        for (int r = 0; r < 4; ++r) {
            const float mnew = fmaxf(mrow[r], rmax[r]);
            alpha[r] = __expf(mrow[r] - mnew);
            mrow[r] = mnew;
            rsum[r] = 0.f;
        }
#pragma unroll
        for (int nt = 0; nt < 4; ++nt)
#pragma unroll
            for (int r = 0; r < 4; ++r) {
                const float pv = __expf(s[nt][r] - mrow[r]);
                s[nt][r] = pv;
                rsum[r] += pv;
            }
#pragma unroll
        for (int r = 0; r < 4; ++r) {
            rsum[r] += __shfl_xor(rsum[r], 1);
            rsum[r] += __shfl_xor(rsum[r], 2);
            rsum[r] += __shfl_xor(rsum[r], 4);
            rsum[r] += __shfl_xor(rsum[r], 8);
            lrow[r] = lrow[r] * alpha[r] + rsum[r];
        }
#pragma unroll
        for (int ntd = 0; ntd < 4; ++ntd)
#pragma unroll
            for (int r = 0; r < 4; ++r) o[ntd][r] *= alpha[r];

        // P -> per-wave rows of QPs (XOR-swizzled layout), re-read in A-layout.
        // Wave w touches only rows w*16..w*16+15 (same rows its Q came from).
#pragma unroll
        for (int nt = 0; nt < 4; ++nt)
#pragma unroll
            for (int r = 0; r < 4; ++r) {
                const int prow = quad * 4 + r;
                const int pc = (nt * 2 + (ln >> 3)) ^ (prow & 7);
                QPs[(w * 16 + prow) * 64 + pc * 8 + (ln & 7)] = f2bf(s[nt][r]);
            }
        asm volatile("s_waitcnt lgkmcnt(0)" ::: "memory");

        const s16x8 aP0 = frag(QPs, w * 16 + ln, quad);
        const s16x8 aP1 = frag(QPs, w * 16 + ln, 4 + quad);
#pragma unroll
        for (int ntd = 0; ntd < 4; ++ntd) {
            const s16x8 b0 = frag(Vc, ntd * 16 + ln, quad);
            const s16x8 b1 = frag(Vc, ntd * 16 + ln, 4 + quad);
            o[ntd] = __builtin_amdgcn_mfma_f32_16x16x32_bf16(aP0, b0, o[ntd], 0, 0, 0);
            o[ntd] = __builtin_amdgcn_mfma_f32_16x16x32_bf16(aP1, b1, o[ntd], 0, 0, 0);
        }
        __syncthreads();   // buffer handoff + drains prefetch for next iter
    }

    // epilogue: normalize + store Z (bf16)
    float invl[4];
#pragma unroll
    for (int r = 0; r < 4; ++r) invl[r] = 1.f / lrow[r];
#pragma unroll
    for (int ntd = 0; ntd < 4; ++ntd)
#pragma unroll
        for (int r = 0; r < 4; ++r) {
            const size_t row = (size_t)(b * NQ + qt * 64 + w * 16 + quad * 4 + r);
            Z[row * EMB + h * HD + ntd * 16 + ln] = f2bf(o[ntd][r] * invl[r]);
        }
}

extern "C" void kernel_launch(void* const* d_in, const int* in_sizes, int n_in,
                              void* d_out, int out_size, void* d_ws, size_t ws_size,
                              hipStream_t stream) {
    const float* x  = (const float*)d_in[0];
    const float* Wq = (const float*)d_in[1];
    const float* Wk = (const float*)d_in[2];
    const float* Wv = (const float*)d_in[3];
    const float* Wo = (const float*)d_in[4];
    const float* bo = (const float*)d_in[5];
    float* out = (float*)d_out;

    const int M = BATCH * NQ;                                   // 4096
    char* ws = (char*)d_ws;
    ushort_t* xb     = (ushort_t*)ws;                                      // 8 MB
    ushort_t* Wqkv_t = (ushort_t*)(ws + (size_t)8  * 1024 * 1024);         // 2.25 MB
    ushort_t* Wo_t   = (ushort_t*)(ws + (size_t)11 * 1024 * 1024);         // 2 MB
    ushort_t* QKV    = (ushort_t*)(ws + (size_t)13 * 1024 * 1024);         // 9.22 MB
    ushort_t* Vt     = (ushort_t*)(ws + (size_t)23 * 1024 * 1024);         // 0.5 MB
    ushort_t* Zb     = (ushort_t*)(ws + (size_t)24 * 1024 * 1024);         // 8 MB

    dim3 blk(256);
    prep<<<dim3(6272), blk, 0, stream>>>(x, Wq, Wk, Wv, Wo, xb, Wqkv_t, Wo_t);
    gemm_bf16<false, true, ushort_t><<<dim3(NKV / 128, M / 64), blk, 0, stream>>>(
        xb, Wqkv_t, nullptr, QKV, Vt, M, NKV, EMB);
    attn_mfma<<<dim3(1024), blk, 0, stream>>>(QKV, Vt, Zb);
    gemm_bf16<true, false, float><<<dim3(EMB / 128, M / 64), blk, 0, stream>>>(
        Zb, Wo_t, bo, out, nullptr, M, EMB, EMB);
}